// Round 1
// baseline (907.748 us; speedup 1.0000x reference)
//
#include <hip/hip_runtime.h>
#include <hip/hip_bf16.h>
#include <stdint.h>

#define B_  2048
#define T_  16
#define F_  768
#define H_  1024
#define G4_ 4096   // 4*H

typedef __attribute__((ext_vector_type(8))) __bf16 bf16x8;
typedef __attribute__((ext_vector_type(4))) float  f32x4;

static __device__ __forceinline__ unsigned short f2bf(float f) {
    union { float f; uint32_t u; } v; v.f = f;
    uint32_t u = v.u;
    uint32_t r = (u + 0x7fffu + ((u >> 16) & 1u)) >> 16;   // RNE
    return (unsigned short)r;
}

static __device__ __forceinline__ float sigf(float x) {
    return 1.0f / (1.0f + __expf(-x));
}
static __device__ __forceinline__ float tanhfast(float x) {
    return 2.0f / (1.0f + __expf(-2.0f * x)) - 1.0f;
}

#define GLOAD_LDS16(gsrc, ldst)                                                       \
    __builtin_amdgcn_global_load_lds((const __attribute__((address_space(1))) void*)(gsrc), \
                                     (__attribute__((address_space(3))) void*)(ldst), \
                                     16, 0, 0)

// ---------------------------------------------------------------- prep kernels

__global__ void convert_x_kernel(const float* __restrict__ x,
                                 unsigned short* __restrict__ xbf, int n4) {
    int idx = blockIdx.x * blockDim.x + threadIdx.x;
    if (idx >= n4) return;
    float4 v = *(const float4*)(x + (size_t)idx * 4);
    ushort4 o;
    o.x = f2bf(v.x); o.y = f2bf(v.y); o.z = f2bf(v.z); o.w = f2bf(v.w);
    *(ushort4*)(xbf + (size_t)idx * 4) = o;
}

// W [K][4096] f32  ->  Wt [4096][K] bf16   (tiled transpose, coalesced both sides)
__global__ void transpose_w_kernel(const float* __restrict__ w,
                                   unsigned short* __restrict__ wt, int K) {
    __shared__ float tile[32][33];
    int nb = blockIdx.x * 32;   // over 4096
    int kb = blockIdx.y * 32;   // over K
    int tx = threadIdx.x, ty = threadIdx.y;
    #pragma unroll
    for (int i = 0; i < 32; i += 8)
        tile[ty + i][tx] = w[(size_t)(kb + ty + i) * G4_ + nb + tx];
    __syncthreads();
    #pragma unroll
    for (int i = 0; i < 32; i += 8)
        wt[(size_t)(nb + ty + i) * K + kb + tx] = f2bf(tile[tx][ty + i]);
}

__global__ void zero_state_kernel(float* __restrict__ c, unsigned short* __restrict__ hbf) {
    int idx = blockIdx.x * blockDim.x + threadIdx.x;   // B*H/4 threads
    float4 z; z.x = z.y = z.z = z.w = 0.0f;
    ((float4*)c)[idx] = z;
    ushort4 zh; zh.x = zh.y = zh.z = zh.w = 0;
    ((ushort4*)hbf)[idx] = zh;
}

// ---------------------------------------------------------------- recurrent GEMM
// gates[B,4096] = [x_t | h] @ [Wih; Whh] + bias     (A: bf16 acts, B: bf16 W^T)
// 128x128 tile, BK=32, 4 waves (2x2), each wave 64x64 via 4x4 frags of 16x16x32.

__global__ __launch_bounds__(256) void lstm_gemm_kernel(
        const unsigned short* __restrict__ xbf,    // [B][T][F] bf16
        const unsigned short* __restrict__ hbf,    // [B][H]    bf16
        const unsigned short* __restrict__ wih_t,  // [4096][768]  bf16 (W_ih^T)
        const unsigned short* __restrict__ whh_t,  // [4096][1024] bf16 (W_hh^T)
        const float* __restrict__ bias,            // [4096]
        float* __restrict__ gates,                 // [B][4096] f32
        int t) {
    __shared__ unsigned short lds_a[128 * 32];
    __shared__ unsigned short lds_b[128 * 32];

    const int tid  = threadIdx.x;
    const int wave = tid >> 6;
    const int lane = tid & 63;
    const int wr = wave >> 1, wc = wave & 1;
    const int bm0 = blockIdx.x * 128;
    const int bn0 = blockIdx.y * 128;

    f32x4 acc[4][4] = {};

    const int lr  = lane >> 2;          // 0..15: row within a 16-row staging group
    const int lk8 = (lane & 3) * 8;     // 0,8,16,24: bf16 elem offset within row

    const int fr = lane & 15;           // frag row/col index
    const int fk = (lane >> 4) * 8;     // frag k offset (0/8/16/24)

    for (int kt = 0; kt < 56; ++kt) {   // 24 tiles from x (K=768), 32 from h (K=1024)
        const int k0 = kt * 32;
        const int r0 = wave * 32;
        // ---- stage A tile rows [r0, r0+32)
        #pragma unroll
        for (int half = 0; half < 2; ++half) {
            int row = r0 + half * 16 + lr;
            const unsigned short* src;
            if (k0 < F_)
                src = xbf + ((size_t)(bm0 + row) * (T_ * F_) + (size_t)t * F_ + k0 + lk8);
            else
                src = hbf + ((size_t)(bm0 + row) * H_ + (k0 - F_) + lk8);
            GLOAD_LDS16(src, lds_a + (size_t)(r0 + half * 16) * 32);
        }
        // ---- stage B tile cols [r0, r0+32)
        #pragma unroll
        for (int half = 0; half < 2; ++half) {
            int col = r0 + half * 16 + lr;
            const unsigned short* src;
            if (k0 < F_)
                src = wih_t + ((size_t)(bn0 + col) * F_ + k0 + lk8);
            else
                src = whh_t + ((size_t)(bn0 + col) * H_ + (k0 - F_) + lk8);
            GLOAD_LDS16(src, lds_b + (size_t)(r0 + half * 16) * 32);
        }
        __syncthreads();   // compiler emits vmcnt(0) drain before s_barrier

        bf16x8 a_frag[4], b_frag[4];
        #pragma unroll
        for (int mi = 0; mi < 4; ++mi) {
            int row = wr * 64 + mi * 16 + fr;
            a_frag[mi] = *(const bf16x8*)(lds_a + row * 32 + fk);
        }
        #pragma unroll
        for (int ni = 0; ni < 4; ++ni) {
            int col = wc * 64 + ni * 16 + fr;
            b_frag[ni] = *(const bf16x8*)(lds_b + col * 32 + fk);
        }
        #pragma unroll
        for (int mi = 0; mi < 4; ++mi)
            #pragma unroll
            for (int ni = 0; ni < 4; ++ni)
                acc[mi][ni] = __builtin_amdgcn_mfma_f32_16x16x32_bf16(
                    a_frag[mi], b_frag[ni], acc[mi][ni], 0, 0, 0);
        __syncthreads();
    }

    // epilogue: gates = acc + bias   (C/D layout: col=lane&15, row=(lane>>4)*4+reg)
    const int fq = lane >> 4;
    #pragma unroll
    for (int ni = 0; ni < 4; ++ni) {
        int col = bn0 + wc * 64 + ni * 16 + fr;
        float bv = bias[col];
        #pragma unroll
        for (int mi = 0; mi < 4; ++mi) {
            #pragma unroll
            for (int r = 0; r < 4; ++r) {
                int row = bm0 + wr * 64 + mi * 16 + fq * 4 + r;
                gates[(size_t)row * G4_ + col] = acc[mi][ni][r] + bv;
            }
        }
    }
}

// ---------------------------------------------------------------- LSTM cell (elementwise)

__global__ void lstm_cell_kernel(const float* __restrict__ gates,
                                 float* __restrict__ c,
                                 unsigned short* __restrict__ hbf,
                                 float* __restrict__ hout,
                                 int writeH) {
    int idx = blockIdx.x * blockDim.x + threadIdx.x;  // B*H/4 threads
    int b = idx >> 8;            // H/4 = 256 vec4 per row
    int j = (idx & 255) * 4;
    const float* gr = gates + (size_t)b * G4_;
    float4 gi = *(const float4*)(gr + j);
    float4 gf = *(const float4*)(gr + H_ + j);
    float4 gg = *(const float4*)(gr + 2 * H_ + j);
    float4 go = *(const float4*)(gr + 3 * H_ + j);
    float* cp = c + (size_t)b * H_ + j;
    float4 cv = *(const float4*)cp;

    float cn[4], hv[4];
    float iv[4] = {gi.x, gi.y, gi.z, gi.w};
    float fv[4] = {gf.x, gf.y, gf.z, gf.w};
    float gv[4] = {gg.x, gg.y, gg.z, gg.w};
    float ov[4] = {go.x, go.y, go.z, go.w};
    float cvv[4] = {cv.x, cv.y, cv.z, cv.w};
    #pragma unroll
    for (int q = 0; q < 4; ++q) {
        cn[q] = sigf(fv[q]) * cvv[q] + sigf(iv[q]) * tanhfast(gv[q]);
        hv[q] = sigf(ov[q]) * tanhfast(cn[q]);
    }
    float4 co; co.x = cn[0]; co.y = cn[1]; co.z = cn[2]; co.w = cn[3];
    *(float4*)cp = co;
    ushort4 hb;
    hb.x = f2bf(hv[0]); hb.y = f2bf(hv[1]); hb.z = f2bf(hv[2]); hb.w = f2bf(hv[3]);
    *(ushort4*)(hbf + (size_t)b * H_ + j) = hb;
    if (writeH) {
        float4 ho; ho.x = hv[0]; ho.y = hv[1]; ho.z = hv[2]; ho.w = hv[3];
        *(float4*)(hout + (size_t)b * H_ + j) = ho;
    }
}

// ---------------------------------------------------------------- launch

extern "C" void kernel_launch(void* const* d_in, const int* in_sizes, int n_in,
                              void* d_out, int out_size, void* d_ws, size_t ws_size,
                              hipStream_t stream) {
    const float* x    = (const float*)d_in[0];   // [B,T,F]
    const float* Wih  = (const float*)d_in[1];   // [F,4H]
    const float* Whh  = (const float*)d_in[2];   // [H,4H]
    const float* bias = (const float*)d_in[3];   // [4H]
    float* out = (float*)d_out;                  // [B,H] flat

    char* ws = (char*)d_ws;
    // ws layout (bytes)
    unsigned short* xbf   = (unsigned short*)(ws);                    // 50,331,648
    unsigned short* wih_t = (unsigned short*)(ws + 50331648);         //  6,291,456
    unsigned short* whh_t = (unsigned short*)(ws + 56623104);         //  8,388,608
    unsigned short* hbf   = (unsigned short*)(ws + 65011712);         //  4,194,304
    float*          c     = (float*)(ws + 69206016);                  //  8,388,608
    float*          gates = (float*)(ws + 77594624);                  // 33,554,432
    // total: 111,149,056 bytes

    // prep
    int n4 = B_ * T_ * F_ / 4;
    hipLaunchKernelGGL(convert_x_kernel, dim3((n4 + 255) / 256), dim3(256), 0, stream,
                       x, xbf, n4);
    hipLaunchKernelGGL(transpose_w_kernel, dim3(G4_ / 32, F_ / 32), dim3(32, 8), 0, stream,
                       Wih, wih_t, F_);
    hipLaunchKernelGGL(transpose_w_kernel, dim3(G4_ / 32, H_ / 32), dim3(32, 8), 0, stream,
                       Whh, whh_t, H_);
    hipLaunchKernelGGL(zero_state_kernel, dim3(B_ * H_ / 4 / 256), dim3(256), 0, stream,
                       c, hbf);

    // recurrence
    for (int t = 0; t < T_; ++t) {
        hipLaunchKernelGGL(lstm_gemm_kernel, dim3(B_ / 128, G4_ / 128), dim3(256), 0, stream,
                           xbf, hbf, wih_t, whh_t, bias, gates, t);
        hipLaunchKernelGGL(lstm_cell_kernel, dim3(B_ * H_ / 4 / 256), dim3(256), 0, stream,
                           gates, c, hbf, out, (t == T_ - 1) ? 1 : 0);
    }
}